// Round 4
// baseline (5669.691 us; speedup 1.0000x reference)
//
#include <hip/hip_runtime.h>
#include <cstdint>
#include <cstddef>

// Problem constants
#define BB     8
#define DIMC   512
#define LL     4096
#define POSN   (BB*LL)        // 32768
#define NG     2
#define NQ     8
#define CS     1024
#define DG     256

// d_out layout (floats): q [8*512*4096] | indices [2*8*4096*8] | losses [16]
#define Q_OFF    0
#define IDX_OFF  16777216
#define LOSS_OFF 17301504

// d_ws layout (float units) — total 39092736 floats = 156.4 MB (same as R2/R3)
#define OFF_WFT   0               // [1536][512] f32
#define OFF_BF    786432          // [512] f32
#define OFF_C2    786944          // [16][1024] f32
#define OFF_QOUT  803328          // [32768][512] f32
#define OFF_CAND  17580544        // [32768][32] u16 candidate ids (524288 f32 units)
#define OFF_LOSSP 18104832        // [16][1024] f32
#define OFF_RHI   18121216        // [2][32768][256] f16 (8388608 f32 units)
#define OFF_RLO   26509824        // [2][32768][256] f16
#define OFF_CHI   34898432        // [16][1024][256] f16 (2097152 f32 units)
#define OFF_CLO   36995584        // [16][1024][256] f16

typedef __attribute__((ext_vector_type(8)))  _Float16 half8;
typedef __attribute__((ext_vector_type(4)))  _Float16 half4;
typedef __attribute__((ext_vector_type(16))) float    f32x16;

#define SPLIT_SCALE 64.0f
#define DOT_ESCALE  4.8828125e-4f   /* 2 / 64^2 */

__device__ __forceinline__ void gl_lds16(const void* g, void* l) {
    __builtin_amdgcn_global_load_lds(
        (__attribute__((address_space(1))) void*)g,
        (__attribute__((address_space(3))) void*)l, 16, 0, 0);
}

__device__ __forceinline__ bool dless(float d, int i, float dr, int ir) {
    return d < dr || (d == dr && i < ir);
}

// insert (nd,ni) into sorted-ascending length-4 list
__device__ __forceinline__ void ins4(float d[4], int id[4], float nd, int ni) {
    if (!dless(nd, ni, d[3], id[3])) return;
    d[3] = nd; id[3] = ni;
    if (dless(d[3], id[3], d[2], id[2])) {
        float tf = d[2]; d[2] = d[3]; d[3] = tf;
        int   ti = id[2]; id[2] = id[3]; id[3] = ti;
    }
    if (dless(d[2], id[2], d[1], id[1])) {
        float tf = d[1]; d[1] = d[2]; d[2] = tf;
        int   ti = id[1]; id[1] = id[2]; id[2] = ti;
    }
    if (dless(d[1], id[1], d[0], id[0])) {
        float tf = d[0]; d[0] = d[1]; d[1] = tf;
        int   ti = id[0]; id[0] = id[1]; id[1] = ti;
    }
}

// top-4 of two sorted-4 lists
__device__ __forceinline__ void merge44(const float ad[4], const int ai[4],
                                        const float bd[4], const int bi[4],
                                        float rd[4], int ri[4]) {
    int ia = 0, ib = 0;
#pragma unroll
    for (int k = 0; k < 4; ++k) {
        float da = ad[ia], db = bd[ib];
        int   xa = ai[ia], xb = bi[ib];
        bool ta = dless(da, xa, db, xb);
        rd[k] = ta ? da : db;
        ri[k] = ta ? xa : xb;
        if (ta) ++ia; else ++ib;
    }
}

// ---------------------------------------------------------------------------
// Fuse conv_enc weights with pre_w:  Wf_t[ik][dd] = sum_j cw[j][i][k]*prew[dd][j]
__global__ __launch_bounds__(256) void k_fuse_w(const float* __restrict__ cw,
                                               const float* __restrict__ prew,
                                               float* __restrict__ wft) {
    __shared__ __align__(16) float As[16][68];
    __shared__ __align__(16) float Bs[16][68];
    int bid = blockIdx.x;
    int mt = bid >> 3, nt = bid & 7;            // 24 x 8
    int m0 = mt * 64, n0 = nt * 64;
    int t = threadIdx.x, tx = t & 15, ty = t >> 4;
    float acc[4][4] = {};
    for (int k0 = 0; k0 < 512; k0 += 16) {
        for (int u = t; u < 16 * 64; u += 256) {
            int kk = u >> 6, mm = u & 63;
            As[kk][mm] = cw[(size_t)(k0 + kk) * 1536 + m0 + mm];
        }
        {
            int r = t >> 2, c4 = t & 3;
            float4 v = *(const float4*)&prew[(size_t)(n0 + r) * 512 + k0 + c4 * 4];
            Bs[c4 * 4 + 0][r] = v.x; Bs[c4 * 4 + 1][r] = v.y;
            Bs[c4 * 4 + 2][r] = v.z; Bs[c4 * 4 + 3][r] = v.w;
        }
        __syncthreads();
#pragma unroll
        for (int k = 0; k < 16; ++k) {
            float4 a = *(const float4*)&As[k][ty * 4];
            float4 b = *(const float4*)&Bs[k][tx * 4];
            float av[4] = {a.x, a.y, a.z, a.w}, bv[4] = {b.x, b.y, b.z, b.w};
#pragma unroll
            for (int i = 0; i < 4; ++i)
#pragma unroll
                for (int j = 0; j < 4; ++j) acc[i][j] += av[i] * bv[j];
        }
        __syncthreads();
    }
#pragma unroll
    for (int i = 0; i < 4; ++i) {
        float4 v = {acc[i][0], acc[i][1], acc[i][2], acc[i][3]};
        *(float4*)&wft[(size_t)(m0 + ty * 4 + i) * 512 + n0 + tx * 4] = v;
    }
}

__global__ void k_bias(const float* __restrict__ prew, const float* __restrict__ preb,
                       const float* __restrict__ ceb, float* __restrict__ bf) {
    int dd = blockIdx.x * 256 + threadIdx.x;
    if (dd < 512) {
        float s = preb[dd];
        for (int j = 0; j < 512; ++j) s += prew[(size_t)dd * 512 + j] * ceb[j];
        bf[dd] = s;
    }
}

// UNCHANGED since R1 (re-rank depends on these exact bits)
__global__ void k_c2(const float* __restrict__ cb, float* __restrict__ c2) {
    int wave = threadIdx.x >> 6, lane = threadIdx.x & 63;
    int row = blockIdx.x * 4 + wave;  // < 16384
    const float* r = cb + (size_t)row * 256;
    float4 v = *(const float4*)&r[lane * 4];
    float s = v.x * v.x + v.y * v.y + v.z * v.z + v.w * v.w;
#pragma unroll
    for (int m = 1; m < 64; m <<= 1) s += __shfl_xor(s, m);
    if (lane == 0) c2[row] = s;
}

// Split codebook into scaled f16 hi/lo: chi+clo == cb*64 to ~2^-22 rel.
__global__ void k_cbsplit(const float* __restrict__ cb,
                          _Float16* __restrict__ chi, _Float16* __restrict__ clo) {
    size_t i = (size_t)blockIdx.x * 256 + threadIdx.x;   // float4 index, 4096 blocks
    float4 v = ((const float4*)cb)[i];
    float sx = v.x * SPLIT_SCALE, sy = v.y * SPLIT_SCALE,
          sz = v.z * SPLIT_SCALE, sw = v.w * SPLIT_SCALE;
    half4 hi, lo;
    hi[0] = (_Float16)sx; hi[1] = (_Float16)sy; hi[2] = (_Float16)sz; hi[3] = (_Float16)sw;
    lo[0] = (_Float16)(sx - (float)hi[0]); lo[1] = (_Float16)(sy - (float)hi[1]);
    lo[2] = (_Float16)(sz - (float)hi[2]); lo[3] = (_Float16)(sw - (float)hi[3]);
    ((half4*)chi)[i] = hi;
    ((half4*)clo)[i] = lo;
}

// Fused conv1d(k=3) + pre-linear; also writes scaled f16 split of h (the q=0 residual)
__global__ __launch_bounds__(256) void k_conv(const float* __restrict__ x,
                                              const float* __restrict__ wft,
                                              const float* __restrict__ bf,
                                              float* __restrict__ h,
                                              _Float16* __restrict__ rhi,
                                              _Float16* __restrict__ rlo) {
    int bid = blockIdx.x;              // 4096 = dt(8) * b(8) * lt(64)
    int dt = bid >> 9;
    int rem = bid & 511;
    int bb = rem >> 6, lt = rem & 63;
    int l0 = lt * 64, d0 = dt * 64;
    int t = threadIdx.x, tx = t & 15, ty = t >> 4;
    __shared__ float Xs[8][68];
    __shared__ __align__(16) float Ws[24][64];
    float acc[4][4] = {};
    const float* xb = x + (size_t)bb * 512 * 4096;
    for (int i0 = 0; i0 < 512; i0 += 8) {
        for (int u = t; u < 8 * 66; u += 256) {
            int ii = u / 66, c = u % 66;
            int gl = l0 + c - 1;
            Xs[ii][c] = (gl >= 0 && gl < 4096) ? xb[(size_t)(i0 + ii) * 4096 + gl] : 0.f;
        }
        for (int u = t; u < 24 * 64; u += 256) {
            int r = u >> 6, c = u & 63;
            Ws[r][c] = wft[(size_t)(i0 * 3 + r) * 512 + d0 + c];
        }
        __syncthreads();
#pragma unroll
        for (int ii = 0; ii < 8; ++ii) {
            float a[6];
#pragma unroll
            for (int j = 0; j < 6; ++j) a[j] = Xs[ii][ty * 4 + j];
#pragma unroll
            for (int k = 0; k < 3; ++k) {
                float4 b = *(const float4*)&Ws[ii * 3 + k][tx * 4];
                float bv[4] = {b.x, b.y, b.z, b.w};
#pragma unroll
                for (int jl = 0; jl < 4; ++jl)
#pragma unroll
                    for (int jd = 0; jd < 4; ++jd) acc[jl][jd] += a[jl + k] * bv[jd];
            }
        }
        __syncthreads();
    }
    int posb = bb * 4096 + l0 + ty * 4;
    int gg = d0 >> 8;
    int dgo = (d0 & 255) + tx * 4;
    const float4 bias = *(const float4*)&bf[d0 + tx * 4];
#pragma unroll
    for (int jl = 0; jl < 4; ++jl) {
        float4 v = {acc[jl][0] + bias.x, acc[jl][1] + bias.y,
                    acc[jl][2] + bias.z, acc[jl][3] + bias.w};
        *(float4*)&h[(size_t)(posb + jl) * 512 + d0 + tx * 4] = v;
        float sx = v.x * SPLIT_SCALE, sy = v.y * SPLIT_SCALE,
              sz = v.z * SPLIT_SCALE, sw = v.w * SPLIT_SCALE;
        half4 hi, lo;
        hi[0] = (_Float16)sx; hi[1] = (_Float16)sy; hi[2] = (_Float16)sz; hi[3] = (_Float16)sw;
        lo[0] = (_Float16)(sx - (float)hi[0]); lo[1] = (_Float16)(sy - (float)hi[1]);
        lo[2] = (_Float16)(sz - (float)hi[2]); lo[3] = (_Float16)(sw - (float)hi[3]);
        size_t so = ((size_t)gg * 32768 + posb + jl) * 256 + dgo;
        *(half4*)&rhi[so] = hi;
        *(half4*)&rlo[so] = lo;
    }
}

// ---------------------------------------------------------------------------
// MFMA dots + TOP-4-per-128-code-tile candidate selection. f16x3 split GEMM,
// concat-K = 768: A' = [Chi, Chi, Clo] (codes), B' = [Rhi, Rlo, Rhi] (positions).
__global__ __launch_bounds__(256) void k_dots_mfma(const _Float16* __restrict__ chi,
                                                   const _Float16* __restrict__ clo,
                                                   const _Float16* __restrict__ rhi,
                                                   const _Float16* __restrict__ rlo,
                                                   const float* __restrict__ c2,
                                                   unsigned short* __restrict__ cand,
                                                   int q, int g) {
    __shared__ _Float16 As[8192];   // 4 mtiles x 4 kc x 64 units x 8 halfs
    __shared__ _Float16 Bs[8192];
    __shared__ float c2s[128];
    __shared__ float cd_s[2][128][4];
    __shared__ int   ci_s[2][128][4];

    const int bid = blockIdx.x;           // 2048 = pos-tile(256) x code-tile(8)
    const int mtile = bid & 7;
    const int m0 = mtile * 128;
    const int p0 = (bid >> 3) * 128;
    const int t = threadIdx.x, w = t >> 6, lam = t & 63;
    const int mtb = (w >> 1) * 2, ntb = (w & 1) * 2;

    const size_t cboff = (size_t)(q * 2 + g) * CS * DG;
    const _Float16* cbh = chi + cboff;
    const _Float16* cbl = clo + cboff;
    const _Float16* rh = rhi + (size_t)g * POSN * DG;
    const _Float16* rl = rlo + (size_t)g * POSN * DG;
    const float* c2q = c2 + (q * 2 + g) * CS;

    if (t < 128) c2s[t] = c2q[m0 + t];

    f32x16 acc[2][2];
#pragma unroll
    for (int i = 0; i < 2; ++i)
#pragma unroll
        for (int j = 0; j < 2; ++j) acc[i][j] = (f32x16)0.f;

    const int srow = lam & 31, shh = lam >> 5;

    for (int s = 0; s < 12; ++s) {
        const int seg = s >> 2;
        const int koff = (s & 3) * 64;
        const _Float16* asrc = (seg < 2) ? cbh : cbl;
        const _Float16* bsrc = (seg == 1) ? rl : rh;
        size_t abase = (size_t)(m0 + w * 32 + srow) * DG + koff + shh * 8;
        size_t bbase = (size_t)(p0 + w * 32 + srow) * DG + koff + shh * 8;
#pragma unroll
        for (int p = 0; p < 4; ++p) {
            gl_lds16(asrc + abase + p * 16, &As[((w * 4 + p) * 64 + lam) * 8]);
            gl_lds16(bsrc + bbase + p * 16, &Bs[((w * 4 + p) * 64 + lam) * 8]);
        }
        __syncthreads();
#pragma unroll
        for (int kc = 0; kc < 4; ++kc) {
            half8 a0 = *(const half8*)&As[((mtb + 0) * 4 + kc) * 512 + lam * 8];
            half8 a1 = *(const half8*)&As[((mtb + 1) * 4 + kc) * 512 + lam * 8];
            half8 b0 = *(const half8*)&Bs[((ntb + 0) * 4 + kc) * 512 + lam * 8];
            half8 b1 = *(const half8*)&Bs[((ntb + 1) * 4 + kc) * 512 + lam * 8];
            acc[0][0] = __builtin_amdgcn_mfma_f32_32x32x16_f16(a0, b0, acc[0][0], 0, 0, 0);
            acc[0][1] = __builtin_amdgcn_mfma_f32_32x32x16_f16(a0, b1, acc[0][1], 0, 0, 0);
            acc[1][0] = __builtin_amdgcn_mfma_f32_32x32x16_f16(a1, b0, acc[1][0], 0, 0, 0);
            acc[1][1] = __builtin_amdgcn_mfma_f32_32x32x16_f16(a1, b1, acc[1][1], 0, 0, 0);
        }
        __syncthreads();
    }

    // epilogue: per-pos top-4 over the block's 128 codes
    const int col = lam & 31, kh = lam >> 5;
#pragma unroll
    for (int nt = 0; nt < 2; ++nt) {
        float td[4] = {1e30f, 1e30f, 1e30f, 1e30f};
        int   ti[4] = {0x7fffffff, 0x7fffffff, 0x7fffffff, 0x7fffffff};
#pragma unroll
        for (int mt = 0; mt < 2; ++mt) {
#pragma unroll
            for (int r = 0; r < 16; ++r) {
                int row = (r & 3) + 8 * (r >> 2) + 4 * kh;
                int code = (mtb + mt) * 32 + row;
                float d = c2s[code] - acc[mt][nt][r] * DOT_ESCALE;
                ins4(td, ti, d, m0 + code);
            }
        }
        float pd[4]; int pi[4];
#pragma unroll
        for (int j = 0; j < 4; ++j) {
            pd[j] = __shfl_xor(td[j], 32);
            pi[j] = __shfl_xor(ti[j], 32);
        }
        float md[4]; int mi[4];
        merge44(td, ti, pd, pi, md, mi);
        if (kh == 0) {
            int pc = (ntb + nt) * 32 + col;
#pragma unroll
            for (int j = 0; j < 4; ++j) {
                cd_s[w >> 1][pc][j] = md[j];
                ci_s[w >> 1][pc][j] = mi[j];
            }
        }
    }
    __syncthreads();
    if (t < 128) {
        float ad[4], bd[4]; int ai[4], bi[4];
#pragma unroll
        for (int j = 0; j < 4; ++j) {
            ad[j] = cd_s[0][t][j]; ai[j] = ci_s[0][t][j];
            bd[j] = cd_s[1][t][j]; bi[j] = ci_s[1][t][j];
        }
        float md[4]; int mi[4];
        merge44(ad, ai, bd, bi, md, mi);
        ushort4 cw;
        cw.x = (unsigned short)mi[0]; cw.y = (unsigned short)mi[1];
        cw.z = (unsigned short)mi[2]; cw.w = (unsigned short)mi[3];
        *(ushort4*)&cand[(size_t)(p0 + t) * 32 + mtile * 4] = cw;
    }
}

// finalize one VQ step: exact re-rank of 32 candidates with R1-BITWISE arithmetic
// (plain ascending-k fp32 FMA chain, d = c2 - 2*dot, strict-< + index tie-break),
// then gather code, update residual (f32 + scaled f16 split), qout, loss, index.
__global__ __launch_bounds__(256) void k_fin(float* __restrict__ hres,
                                             const float* __restrict__ cb,
                                             const float* __restrict__ c2,
                                             const unsigned short* __restrict__ cand,
                                             float* __restrict__ qout,
                                             float* __restrict__ lossp,
                                             float* __restrict__ idx_out,
                                             _Float16* __restrict__ rhi,
                                             _Float16* __restrict__ rlo,
                                             int q, int g) {
    __shared__ float rs[4][8][256];
    __shared__ float ls[4];
    int t = threadIdx.x, wave = t >> 6, lane = t & 63;
    const float* cbq = cb + (size_t)(q * 2 + g) * CS * DG;
    const float* c2q = c2 + (q * 2 + g) * CS;
    int pbase = blockIdx.x * 32 + wave * 8;   // grid 1024, 32 pos/block

    // Phase A: load the 8 residual rows (kept in regs, mirrored to LDS)
    float4 rv[8];
#pragma unroll
    for (int i = 0; i < 8; ++i) {
        size_t ro = (size_t)(pbase + i) * 512 + g * 256 + lane * 4;
        rv[i] = *(const float4*)&hres[ro];
        *(float4*)&rs[wave][i][lane * 4] = rv[i];
    }

    // Phase B: exact re-rank. lane = cslot(0..31) x posg(0..1); 4 passes x 2 pos.
    int cslot = lane & 31, posg = lane >> 5;
    int resIdx[4];
#pragma unroll
    for (int p = 0; p < 4; ++p) {
        int i = p * 2 + posg;
        int pos = pbase + i;
        int cidx = (int)cand[(size_t)pos * 32 + cslot];
        const float* crow = cbq + (size_t)cidx * 256;
        float acc = 0.f;
#pragma unroll 8
        for (int k4 = 0; k4 < 64; ++k4) {
            float4 cv = *(const float4*)&crow[k4 * 4];
            float4 rr = *(const float4*)&rs[wave][i][k4 * 4];
            acc = fmaf(cv.x, rr.x, acc);
            acc = fmaf(cv.y, rr.y, acc);
            acc = fmaf(cv.z, rr.z, acc);
            acc = fmaf(cv.w, rr.w, acc);
        }
        float bd = c2q[cidx] - 2.f * acc;
        int bi = cidx;
#pragma unroll
        for (int m = 1; m < 32; m <<= 1) {
            float od = __shfl_xor(bd, m);
            int   oi = __shfl_xor(bi, m);
            if (dless(od, oi, bd, bi)) { bd = od; bi = oi; }
        }
        resIdx[p] = bi;   // uniform within each 32-lane half
    }

    // Phase C: update
    float lsum = 0.f;
#pragma unroll
    for (int i = 0; i < 8; ++i) {
        int pos = pbase + i;
        int idx = __shfl(resIdx[i >> 1], (i & 1) * 32);
        float4 cv = *(const float4*)&cbq[(size_t)idx * 256 + lane * 4];
        size_t ro = (size_t)pos * 512 + g * 256 + lane * 4;
        float4 rn = {rv[i].x - cv.x, rv[i].y - cv.y, rv[i].z - cv.z, rv[i].w - cv.w};
        *(float4*)&hres[ro] = rn;
        if (q == 0) {
            *(float4*)&qout[ro] = cv;
        } else {
            float4 qv = *(const float4*)&qout[ro];
            qv.x += cv.x; qv.y += cv.y; qv.z += cv.z; qv.w += cv.w;
            *(float4*)&qout[ro] = qv;
        }
        if (q < 7) {
            float sx = rn.x * SPLIT_SCALE, sy = rn.y * SPLIT_SCALE,
                  sz = rn.z * SPLIT_SCALE, sw = rn.w * SPLIT_SCALE;
            half4 hi, lo;
            hi[0] = (_Float16)sx; hi[1] = (_Float16)sy;
            hi[2] = (_Float16)sz; hi[3] = (_Float16)sw;
            lo[0] = (_Float16)(sx - (float)hi[0]); lo[1] = (_Float16)(sy - (float)hi[1]);
            lo[2] = (_Float16)(sz - (float)hi[2]); lo[3] = (_Float16)(sw - (float)hi[3]);
            size_t so = ((size_t)g * POSN + pos) * 256 + lane * 4;
            *(half4*)&rhi[so] = hi;
            *(half4*)&rlo[so] = lo;
        }
        lsum += rn.x * rn.x + rn.y * rn.y + rn.z * rn.z + rn.w * rn.w;
        if (lane == 0)
            idx_out[(size_t)(g * 32768 + pos) * 8 + q] = (float)idx;
    }
#pragma unroll
    for (int m = 1; m < 64; m <<= 1) lsum += __shfl_xor(lsum, m);
    if (lane == 0) ls[wave] = lsum;
    __syncthreads();
    if (t == 0) lossp[(size_t)(g * 8 + q) * 1024 + blockIdx.x] = ls[0] + ls[1] + ls[2] + ls[3];
}

// post-linear with transposed store
__global__ __launch_bounds__(256) void k_post(const float* __restrict__ qout,
                                              const float* __restrict__ pw,
                                              const float* __restrict__ pb,
                                              float* __restrict__ out) {
    __shared__ __align__(16) float As[16][68];
    __shared__ __align__(16) float Bs[16][68];
    int bid = blockIdx.x;            // 4096 = mt(512) * nt(8)
    int mt = bid >> 3, nt = bid & 7;
    int p0 = mt * 64, d0 = nt * 64;
    int t = threadIdx.x, tx = t & 15, ty = t >> 4;
    float acc[4][4] = {};
    for (int k0 = 0; k0 < 512; k0 += 16) {
        int r = t >> 2, c4 = t & 3;
        {
            float4 v = *(const float4*)&qout[(size_t)(p0 + r) * 512 + k0 + c4 * 4];
            As[c4 * 4 + 0][r] = v.x; As[c4 * 4 + 1][r] = v.y;
            As[c4 * 4 + 2][r] = v.z; As[c4 * 4 + 3][r] = v.w;
        }
        {
            float4 v = *(const float4*)&pw[(size_t)(d0 + r) * 512 + k0 + c4 * 4];
            Bs[c4 * 4 + 0][r] = v.x; Bs[c4 * 4 + 1][r] = v.y;
            Bs[c4 * 4 + 2][r] = v.z; Bs[c4 * 4 + 3][r] = v.w;
        }
        __syncthreads();
#pragma unroll
        for (int k = 0; k < 16; ++k) {
            float4 a = *(const float4*)&As[k][tx * 4];
            float4 b = *(const float4*)&Bs[k][ty * 4];
            float av[4] = {a.x, a.y, a.z, a.w}, bv[4] = {b.x, b.y, b.z, b.w};
#pragma unroll
            for (int i = 0; i < 4; ++i)
#pragma unroll
                for (int j = 0; j < 4; ++j) acc[i][j] += av[i] * bv[j];
        }
        __syncthreads();
    }
    int bb = p0 >> 12, l0 = p0 & 4095;
#pragma unroll
    for (int jd = 0; jd < 4; ++jd) {
        int dd = d0 + ty * 4 + jd;
        float bias = pb[dd];
        float4 v = {acc[0][jd] + bias, acc[1][jd] + bias,
                    acc[2][jd] + bias, acc[3][jd] + bias};
        *(float4*)&out[((size_t)bb * 512 + dd) * 4096 + l0 + tx * 4] = v;
    }
}

__global__ void k_lossfin(const float* __restrict__ lossp, float* __restrict__ out) {
    int gq = blockIdx.x;   // 16 blocks
    float s = 0.f;
    for (int u = threadIdx.x; u < 1024; u += 256) s += lossp[(size_t)gq * 1024 + u];
    int wave = threadIdx.x >> 6, lane = threadIdx.x & 63;
#pragma unroll
    for (int m = 1; m < 64; m <<= 1) s += __shfl_xor(s, m);
    __shared__ float sh[4];
    if (lane == 0) sh[wave] = s;
    __syncthreads();
    if (threadIdx.x == 0)
        out[gq] = (sh[0] + sh[1] + sh[2] + sh[3]) * (1.f / (8.f * 4096.f * 256.f));
}

extern "C" void kernel_launch(void* const* d_in, const int* in_sizes, int n_in,
                              void* d_out, int out_size, void* d_ws, size_t ws_size,
                              hipStream_t stream) {
    (void)in_sizes; (void)n_in; (void)out_size; (void)ws_size;
    const float* x     = (const float*)d_in[0];
    const float* cew   = (const float*)d_in[1];
    const float* ceb   = (const float*)d_in[2];
    const float* prew  = (const float*)d_in[3];
    const float* preb  = (const float*)d_in[4];
    const float* cb    = (const float*)d_in[5];
    const float* postw = (const float*)d_in[6];
    const float* postb = (const float*)d_in[7];
    // d_in[8], d_in[9]: conv_dec weights — result discarded by reference, skip.

    float* out = (float*)d_out;
    float* ws  = (float*)d_ws;
    float* wft   = ws + OFF_WFT;
    float* bf    = ws + OFF_BF;
    float* c2    = ws + OFF_C2;
    float* qout  = ws + OFF_QOUT;
    unsigned short* cand = (unsigned short*)(ws + OFF_CAND);
    float* lossp = ws + OFF_LOSSP;
    _Float16* rhi = (_Float16*)(ws + OFF_RHI);
    _Float16* rlo = (_Float16*)(ws + OFF_RLO);
    _Float16* chi = (_Float16*)(ws + OFF_CHI);
    _Float16* clo = (_Float16*)(ws + OFF_CLO);
    float* h = out;  // q-region of d_out doubles as residual scratch; overwritten by k_post

    k_fuse_w<<<192, 256, 0, stream>>>(cew, prew, wft);
    k_bias<<<2, 256, 0, stream>>>(prew, preb, ceb, bf);
    k_c2<<<4096, 256, 0, stream>>>(cb, c2);
    k_cbsplit<<<4096, 256, 0, stream>>>(cb, chi, clo);
    k_conv<<<4096, 256, 0, stream>>>(x, wft, bf, h, rhi, rlo);
    for (int q = 0; q < 8; ++q) {
        for (int g = 0; g < 2; ++g) {
            k_dots_mfma<<<2048, 256, 0, stream>>>(chi, clo, rhi, rlo, c2,
                                                  cand, q, g);
            k_fin<<<1024, 256, 0, stream>>>(h, cb, c2, cand, qout, lossp,
                                            out + IDX_OFF, rhi, rlo, q, g);
        }
    }
    k_post<<<4096, 256, 0, stream>>>(qout, postw, postb, out);
    k_lossfin<<<16, 256, 0, stream>>>(lossp, out + LOSS_OFF);
}